// Round 7
// baseline (243.169 us; speedup 1.0000x reference)
//
#include <hip/hip_runtime.h>
#include <hip/hip_bf16.h>
#include <math.h>

#define N_TOK 16384
#define DIM   256
#define HID   512
#define NEXP  16
#define NSLOT (N_TOK * 2)
#define RT    32
#define MAXT  (NSLOT / RT + NEXP)   // 1040 = 8*130 upper bound on total m-tiles

typedef __attribute__((ext_vector_type(8))) short bf16x8;
typedef __attribute__((ext_vector_type(4))) float f32x4;
#define MFMA(a, b, c) __builtin_amdgcn_mfma_f32_16x16x32_bf16(a, b, c, 0, 0, 0)

__device__ __forceinline__ unsigned short f2b(float f) {
  union { float f; unsigned int i; } c; c.f = f;
  unsigned int r = c.i + 0x7FFFu + ((c.i >> 16) & 1u);  // RNE
  return (unsigned short)(r >> 16);
}

// tanh-form GELU via hw exp2/rcp
__device__ __forceinline__ float gelu_f(float v) {
  float v2 = v * v;
  float u2 = v * fmaf(0.10294322f, v2, 2.3022082f);
  float s  = __builtin_amdgcn_exp2f(u2);
  float r  = __builtin_amdgcn_rcpf(1.0f + s);
  return fmaf(-v, r, v);
}

// ---------- prep: W1,W2 -> bf16 fragment-major ----------
__global__ __launch_bounds__(256) void prep_kernel(
    const float* __restrict__ W1, const float* __restrict__ W2,
    unsigned short* __restrict__ W1f, unsigned short* __restrict__ W2f)
{
  int id = blockIdx.x * 256 + threadIdx.x;
  if (id < 524288) {                       // W1f: ((e*8+kb)*512+h)*32 + (d%32)
    int i4 = id * 4;
    int inner = i4 & 31;
    int h  = (i4 >> 5) & 511;
    int kb = (i4 >> 14) & 7;
    int e  = i4 >> 17;
    const float* src = W1 + ((size_t)(e * 256 + kb * 32 + inner) * 512 + h);
    ushort4 o;
    o.x = f2b(src[0]); o.y = f2b(src[512]); o.z = f2b(src[1024]); o.w = f2b(src[1536]);
    *(ushort4*)(W1f + i4) = o;
  } else {                                 // W2f: ((e*16+kb)*256+d2)*32 + (h%32)
    int i4 = (id - 524288) * 4;
    int inner = i4 & 31;
    int d2 = (i4 >> 5) & 255;
    int kb = (i4 >> 13) & 15;
    int e  = i4 >> 17;
    const float* src = W2 + ((size_t)(e * 512 + kb * 32 + inner) * 256 + d2);
    ushort4 o;
    o.x = f2b(src[0]); o.y = f2b(src[256]); o.z = f2b(src[512]); o.w = f2b(src[768]);
    *(ushort4*)(W2f + i4) = o;
  }
}

// ---------- router: one wave per token (+ bf16 x copy) ----------
__global__ __launch_bounds__(256) void router_kernel(
    const float* __restrict__ x, const float* __restrict__ Wr,
    float* __restrict__ probs_out, float* __restrict__ topi_out,
    float* __restrict__ topw, int* __restrict__ sel, float* __restrict__ g_partial,
    unsigned short* __restrict__ xb)
{
  __shared__ float sp[16];
  int tid = threadIdx.x;
  int wv = tid >> 6, lane = tid & 63;
  int tok = blockIdx.x * 4 + wv;
  int e = lane & 15, q = lane >> 4;
  if (tid < 16) sp[tid] = 0.f;
  __syncthreads();

  const float4* xr = (const float4*)(x + (size_t)tok * DIM + q * 64);
  const float4* wr = (const float4*)(Wr + (size_t)e * DIM + q * 64);
  float a0 = 0.f, a1 = 0.f, a2 = 0.f, a3 = 0.f;
  #pragma unroll
  for (int i = 0; i < 16; ++i) {
    float4 xa = xr[i], wa = wr[i];
    a0 += xa.x * wa.x; a1 += xa.y * wa.y; a2 += xa.z * wa.z; a3 += xa.w * wa.w;
  }
  float lg = (a0 + a1) + (a2 + a3);
  lg += __shfl_xor(lg, 16, 64);
  lg += __shfl_xor(lg, 32, 64);           // every lane: full logit for its e

  float mx = lg;
  #pragma unroll
  for (int o = 1; o < 16; o <<= 1) mx = fmaxf(mx, __shfl_xor(mx, o, 64));
  float ex = expf(lg - mx);
  float ssum = ex;
  #pragma unroll
  for (int o = 1; o < 16; o <<= 1) ssum += __shfl_xor(ssum, o, 64);
  float p = ex / ssum;

  if (lane < 16) {
    probs_out[(size_t)tok * NEXP + e] = p;
    atomicAdd(&sp[e], p);
  }

  // bf16 copy of this token's x row (4 floats per lane, coalesced)
  {
    float4 xc = *(const float4*)(x + (size_t)tok * DIM + lane * 4);
    ushort4 o;
    o.x = f2b(xc.x); o.y = f2b(xc.y); o.z = f2b(xc.z); o.w = f2b(xc.w);
    *(ushort4*)(xb + (size_t)tok * DIM + lane * 4) = o;
  }

  // top-2 argmax (strict >, low index wins)
  float p1 = p; int i1 = e;
  #pragma unroll
  for (int o = 1; o < 16; o <<= 1) {
    float po = __shfl_xor(p1, o, 64); int io = __shfl_xor(i1, o, 64);
    if (po > p1 || (po == p1 && io < i1)) { p1 = po; i1 = io; }
  }
  float pm = (e == i1) ? -1.f : p;
  float p2 = pm; int i2 = e;
  #pragma unroll
  for (int o = 1; o < 16; o <<= 1) {
    float po = __shfl_xor(p2, o, 64); int io = __shfl_xor(i2, o, 64);
    if (po > p2 || (po == p2 && io < i2)) { p2 = po; i2 = io; }
  }
  if (lane == 0) {
    float rs = 1.0f / (p1 + p2 + 1e-9f);
    int s0 = tok * 2;
    topw[s0] = p1 * rs;  topw[s0 + 1] = p2 * rs;
    sel[s0] = i1;        sel[s0 + 1] = i2;
    topi_out[s0] = (float)i1;  topi_out[s0 + 1] = (float)i2;
  }
  __syncthreads();
  if (tid < 16) g_partial[(size_t)tid * 4096 + blockIdx.x] = sp[tid];
}

// ---------- scatter: parallel bucket fill into per-expert arenas ----------
__global__ __launch_bounds__(256) void scatter_kernel(
    const int* __restrict__ sel, const float* __restrict__ topw,
    int* __restrict__ cursors, int* __restrict__ tok_of_pos, float* __restrict__ w_of_pos)
{
  __shared__ int bcnt[16];
  __shared__ int bbase[16];
  int tid = threadIdx.x;
  if (tid < 16) bcnt[tid] = 0;
  __syncthreads();
  int s = blockIdx.x * 256 + tid;      // NSLOT = 128*256 exact
  int e = sel[s];
  int my = atomicAdd(&bcnt[e], 1);
  __syncthreads();
  if (tid < 16) bbase[tid] = atomicAdd(&cursors[tid], bcnt[tid]);
  __syncthreads();
  int idx = e * NSLOT + bbase[e] + my;
  tok_of_pos[idx] = s >> 1;
  w_of_pos[idx]   = topw[s];
}

// ---------- stats: lb_loss + XCD-grouped tile table (parallel fill) ----------
__global__ __launch_bounds__(1024) void stats_kernel(
    const int* __restrict__ cursors, const float* __restrict__ g_partial,
    int* __restrict__ perm, float* __restrict__ lb_out)
{
  __shared__ float sp[16];
  __shared__ int nt[16];
  __shared__ int P[9];
  int tid = threadIdx.x;
  int wv = tid >> 6, lane = tid & 63;
  float sacc = 0.f;
  #pragma unroll
  for (int j = 0; j < 64; ++j) sacc += g_partial[(size_t)wv * 4096 + j * 64 + lane];
  #pragma unroll
  for (int o = 32; o; o >>= 1) sacc += __shfl_xor(sacc, o, 64);
  if (lane == 0) sp[wv] = sacc;
  if (tid < 16) nt[tid] = (cursors[tid] + RT - 1) / RT;
  __syncthreads();

  if (tid == 0) {
    float acc = 0.f;
    for (int e = 0; e < NEXP; ++e)
      acc += ((float)cursors[e] / (32768.0f + 1e-9f)) * (sp[e] * (1.0f / 16384.0f));
    lb_out[0] = 0.01f * 16.0f * acc;
    int pp = 0;
    for (int g = 0; g < 8; ++g) { P[g] = pp; pp += nt[g] + nt[g + 8]; }
    P[8] = pp;
  }
  __syncthreads();

  for (int t = tid; t < MAXT; t += 1024) {
    int g = 0;
    #pragma unroll
    for (int gg = 1; gg < 8; ++gg) if (t >= P[gg]) g = gg;
    int v = -1;
    if (t < P[8]) {
      int r = t - P[g];
      int e = (r < nt[g]) ? g : g + 8;
      int mt = (r < nt[g]) ? r : r - nt[g];
      v = (e << 16) | mt;
    }
    perm[t] = v;
  }
}

// ---------- fused FFN: 8 waves, MFMA GEMM1(gelu) + GEMM2, atomic scatter ----------
__global__ __launch_bounds__(512, 4) void ffn_kernel(
    const unsigned short* __restrict__ xb,
    const unsigned short* __restrict__ W1f, const unsigned short* __restrict__ W2f,
    const int* __restrict__ cursors, const int* __restrict__ perm,
    const int* __restrict__ tok_of_pos, const float* __restrict__ w_of_pos,
    float* __restrict__ zbuf)
{
  __shared__ __align__(16) unsigned short As[8 * 32 * 32];    // 16 KB
  __shared__ __align__(16) unsigned short Hs[16 * 32 * 32];   // 32 KB
  __shared__ float rwS[RT];
  __shared__ int   tokS[RT];

  int b = blockIdx.x;
  int rr = (b & 7) * (MAXT / 8) + (b >> 3);   // XCD-pinned tile pick
  int pv = perm[rr];
  if (pv < 0) return;
  int e = pv >> 16, mtile = pv & 0xFFFF;
  int cnt = cursors[e];
  int base = e * NSLOT;
  int m0 = mtile * RT;

  int tid = threadIdx.x;
  if (tid < RT) {
    int rl = m0 + tid;
    tokS[tid] = (rl < cnt) ? tok_of_pos[base + rl] : -1;
    rwS[tid]  = (rl < cnt) ? w_of_pos[base + rl] : 0.f;
  }
  __syncthreads();

  // gather X rows (bf16) into As fragment layout (coalesced per half-wave)
  #pragma unroll
  for (int q = 0; q < 2; ++q) {
    int idx = q * 512 + tid;
    int row = idx >> 5, cb = idx & 31;
    int tk = tokS[row];
    bf16x8 v = {0, 0, 0, 0, 0, 0, 0, 0};
    if (tk >= 0) v = *(const bf16x8*)(xb + (size_t)tk * DIM + cb * 8);
    *(bf16x8*)&As[(cb >> 2) * 1024 + (cb & 3) * 8 + row * 32] = v;
  }
  __syncthreads();

  int lane = tid & 63;
  int w = tid >> 6;              // wave 0..7
  int l15 = lane & 15, g = lane >> 4;

  // ---- GEMM1: H = gelu(A @ W1e); wave w owns H cols [w*64, w*64+64) ----
  bf16x8 af[2][8];
  #pragma unroll
  for (int mf = 0; mf < 2; ++mf)
    #pragma unroll
    for (int kb = 0; kb < 8; ++kb)
      af[mf][kb] = *(bf16x8*)&As[kb * 1024 + (mf * 16 + l15) * 32 + g * 8];

  const unsigned short* W1e = W1f + (size_t)e * (8 * 512 * 32);
  #pragma unroll
  for (int cf = 0; cf < 4; ++cf) {
    int col0 = w * 64 + cf * 16;
    f32x4 ac0 = {0.f, 0.f, 0.f, 0.f}, ac1 = {0.f, 0.f, 0.f, 0.f};
    #pragma unroll
    for (int kb = 0; kb < 8; ++kb) {
      bf16x8 bfr = *(const bf16x8*)(W1e + (size_t)(kb * 512 + col0 + l15) * 32 + g * 8);
      ac0 = MFMA(af[0][kb], bfr, ac0);
      ac1 = MFMA(af[1][kb], bfr, ac1);
    }
    int col = col0 + l15;
    int kbo = (col >> 5) * 1024 + (col & 31);
    #pragma unroll
    for (int reg = 0; reg < 4; ++reg) {
      int row0 = g * 4 + reg;
      Hs[kbo + row0 * 32]        = f2b(gelu_f(ac0[reg]));
      Hs[kbo + (row0 + 16) * 32] = f2b(gelu_f(ac1[reg]));
    }
  }
  __syncthreads();

  // ---- GEMM2: y = (H @ W2e) * w; wave w owns y cols [w*32, w*32+32) ----
  const unsigned short* W2e = W2f + (size_t)e * (16 * 256 * 32);
  #pragma unroll
  for (int cf = 0; cf < 2; ++cf) {
    int col0 = w * 32 + cf * 16;
    bf16x8 bfr[16];
    #pragma unroll
    for (int kb = 0; kb < 16; ++kb)
      bfr[kb] = *(const bf16x8*)(W2e + (size_t)(kb * 256 + col0 + l15) * 32 + g * 8);

    #pragma unroll
    for (int mf = 0; mf < 2; ++mf) {
      f32x4 ac = {0.f, 0.f, 0.f, 0.f};
      #pragma unroll
      for (int kb = 0; kb < 16; ++kb) {
        bf16x8 hfr = *(bf16x8*)&Hs[kb * 1024 + (mf * 16 + l15) * 32 + g * 8];
        ac = MFMA(hfr, bfr[kb], ac);
      }
      int col = col0 + l15;
      #pragma unroll
      for (int reg = 0; reg < 4; ++reg) {
        int row = mf * 16 + g * 4 + reg;
        int t = tokS[row];
        if (t >= 0) atomicAdd(zbuf + (size_t)t * DIM + col, ac[reg] * rwS[row]);
      }
    }
  }
}

// ---------- combine + residual + LayerNorm ----------
__global__ __launch_bounds__(256) void combine_ln_kernel(
    const float* __restrict__ x, const float* __restrict__ zbuf,
    const float* __restrict__ gamma, const float* __restrict__ beta,
    float* __restrict__ outp)
{
  int wv = threadIdx.x >> 6, lane = threadIdx.x & 63;
  int tok = blockIdx.x * 4 + wv;
  int d0 = lane << 2;
  float4 xv = *(const float4*)(x + (size_t)tok * DIM + d0);
  float4 mv = *(const float4*)(zbuf + (size_t)tok * DIM + d0);
  float z0 = xv.x + mv.x, z1 = xv.y + mv.y, z2 = xv.z + mv.z, z3 = xv.w + mv.w;
  float s = z0 + z1 + z2 + z3;
  float q = z0 * z0 + z1 * z1 + z2 * z2 + z3 * z3;
  #pragma unroll
  for (int off = 32; off > 0; off >>= 1) {
    s += __shfl_xor(s, off, 64);
    q += __shfl_xor(q, off, 64);
  }
  float mu  = s * (1.0f / 256.0f);
  float var = q * (1.0f / 256.0f) - mu * mu;
  float inv = rsqrtf(var + 1e-5f);
  float4 gv = *(const float4*)(gamma + d0);
  float4 bv = *(const float4*)(beta + d0);
  float4 ov;
  ov.x = (z0 - mu) * inv * gv.x + bv.x;
  ov.y = (z1 - mu) * inv * gv.y + bv.y;
  ov.z = (z2 - mu) * inv * gv.z + bv.z;
  ov.w = (z3 - mu) * inv * gv.w + bv.w;
  *(float4*)(outp + (size_t)tok * DIM + d0) = ov;
}

extern "C" void kernel_launch(void* const* d_in, const int* in_sizes, int n_in,
                              void* d_out, int out_size, void* d_ws, size_t ws_size,
                              hipStream_t stream)
{
  const float* x     = (const float*)d_in[0];
  const float* Wr    = (const float*)d_in[1];
  const float* W1    = (const float*)d_in[2];
  const float* W2    = (const float*)d_in[3];
  const float* gamma = (const float*)d_in[4];
  const float* beta  = (const float*)d_in[5];

  float* ob = (float*)d_out;
  float* out_main  = ob;
  float* lb_out    = ob + (size_t)N_TOK * DIM;
  float* probs_out = ob + (size_t)N_TOK * DIM + 1;
  float* topi_out  = ob + (size_t)N_TOK * DIM + 1 + (size_t)N_TOK * NEXP;

  char* ws = (char*)d_ws;
  int*   cursors    = (int*)(ws + 0);                    // 64 B [zeroed]
  int*   perm       = (int*)(ws + 1024);                 // 1040 ints
  float* g_partial  = (float*)(ws + 65536);              // 256 KB
  float* topw       = (float*)(ws + 327680);             // 128 KB
  int*   sel        = (int*)(ws + 458752);               // 128 KB
  int*   tok_of_pos = (int*)(ws + 589824);               // 2 MB (16 arenas x 32768)
  float* w_of_pos   = (float*)(ws + 2686976);            // 2 MB
  unsigned short* xb  = (unsigned short*)(ws + 4980736);    // 8 MB
  unsigned short* W1f = (unsigned short*)(ws + 13369344);   // 4 MB
  unsigned short* W2f = (unsigned short*)(ws + 17563648);   // 4 MB
  float* zbuf       = (float*)(ws + 21757952);              // 16 MB; total ~36.7 MB

  hipMemsetAsync(cursors, 0, 64, stream);
  hipMemsetAsync(zbuf, 0, (size_t)N_TOK * DIM * 4, stream);
  prep_kernel<<<4096, 256, 0, stream>>>(W1, W2, W1f, W2f);
  router_kernel<<<N_TOK / 4, 256, 0, stream>>>(x, Wr, probs_out, topi_out, topw, sel, g_partial, xb);
  scatter_kernel<<<NSLOT / 256, 256, 0, stream>>>(sel, topw, cursors, tok_of_pos, w_of_pos);
  stats_kernel<<<1, 1024, 0, stream>>>(cursors, g_partial, perm, lb_out);
  ffn_kernel<<<MAXT, 512, 0, stream>>>(xb, W1f, W2f, cursors, perm, tok_of_pos, w_of_pos, zbuf);
  combine_ln_kernel<<<N_TOK / 4, 256, 0, stream>>>(x, zbuf, gamma, beta, out_main);
}

// Round 9
// 225.949 us; speedup vs baseline: 1.0762x; 1.0762x over previous
//
#include <hip/hip_runtime.h>
#include <hip/hip_bf16.h>
#include <math.h>

#define N_TOK 16384
#define DIM   256
#define HID   512
#define NEXP  16
#define NSLOT (N_TOK * 2)
#define RT    64
#define MAXT  (NSLOT / RT + NEXP)   // 528 = 8*66
#define XCDC  (MAXT / 8)            // 66

typedef __attribute__((ext_vector_type(8))) short bf16x8;
typedef __attribute__((ext_vector_type(4))) float f32x4;
#define MFMA(a, b, c) __builtin_amdgcn_mfma_f32_16x16x32_bf16(a, b, c, 0, 0, 0)

__device__ __forceinline__ unsigned short f2b(float f) {
  union { float f; unsigned int i; } c; c.f = f;
  unsigned int r = c.i + 0x7FFFu + ((c.i >> 16) & 1u);  // RNE
  return (unsigned short)(r >> 16);
}

// tanh-form GELU via hw exp2/rcp
__device__ __forceinline__ float gelu_f(float v) {
  float v2 = v * v;
  float u2 = v * fmaf(0.10294322f, v2, 2.3022082f);
  float s  = __builtin_amdgcn_exp2f(u2);
  float r  = __builtin_amdgcn_rcpf(1.0f + s);
  return fmaf(-v, r, v);
}

// ---------- prep: W1,W2 -> bf16 fragment-major ----------
__global__ __launch_bounds__(256) void prep_kernel(
    const float* __restrict__ W1, const float* __restrict__ W2,
    unsigned short* __restrict__ W1f, unsigned short* __restrict__ W2f)
{
  int id = blockIdx.x * 256 + threadIdx.x;
  if (id < 524288) {                       // W1f: ((e*8+kb)*512+h)*32 + (d%32)
    int i4 = id * 4;
    int inner = i4 & 31;
    int h  = (i4 >> 5) & 511;
    int kb = (i4 >> 14) & 7;
    int e  = i4 >> 17;
    const float* src = W1 + ((size_t)(e * 256 + kb * 32 + inner) * 512 + h);
    ushort4 o;
    o.x = f2b(src[0]); o.y = f2b(src[512]); o.z = f2b(src[1024]); o.w = f2b(src[1536]);
    *(ushort4*)(W1f + i4) = o;
  } else {                                 // W2f: ((e*16+kb)*256+d2)*32 + (h%32)
    int i4 = (id - 524288) * 4;
    int inner = i4 & 31;
    int d2 = (i4 >> 5) & 255;
    int kb = (i4 >> 13) & 15;
    int e  = i4 >> 17;
    const float* src = W2 + ((size_t)(e * 512 + kb * 32 + inner) * 256 + d2);
    ushort4 o;
    o.x = f2b(src[0]); o.y = f2b(src[256]); o.z = f2b(src[512]); o.w = f2b(src[768]);
    *(ushort4*)(W2f + i4) = o;
  }
}

// ---------- router: one wave per token (+ bf16 x copy) ----------
__global__ __launch_bounds__(256) void router_kernel(
    const float* __restrict__ x, const float* __restrict__ Wr,
    float* __restrict__ probs_out, float* __restrict__ topi_out,
    float* __restrict__ topw, int* __restrict__ sel, float* __restrict__ g_partial,
    unsigned short* __restrict__ xb)
{
  __shared__ float sp[16];
  int tid = threadIdx.x;
  int wv = tid >> 6, lane = tid & 63;
  int tok = blockIdx.x * 4 + wv;
  int e = lane & 15, q = lane >> 4;
  if (tid < 16) sp[tid] = 0.f;
  __syncthreads();

  const float4* xr = (const float4*)(x + (size_t)tok * DIM + q * 64);
  const float4* wr = (const float4*)(Wr + (size_t)e * DIM + q * 64);
  float a0 = 0.f, a1 = 0.f, a2 = 0.f, a3 = 0.f;
  #pragma unroll
  for (int i = 0; i < 16; ++i) {
    float4 xa = xr[i], wa = wr[i];
    a0 += xa.x * wa.x; a1 += xa.y * wa.y; a2 += xa.z * wa.z; a3 += xa.w * wa.w;
  }
  float lg = (a0 + a1) + (a2 + a3);
  lg += __shfl_xor(lg, 16, 64);
  lg += __shfl_xor(lg, 32, 64);           // every lane: full logit for its e

  float mx = lg;
  #pragma unroll
  for (int o = 1; o < 16; o <<= 1) mx = fmaxf(mx, __shfl_xor(mx, o, 64));
  float ex = expf(lg - mx);
  float ssum = ex;
  #pragma unroll
  for (int o = 1; o < 16; o <<= 1) ssum += __shfl_xor(ssum, o, 64);
  float p = ex / ssum;

  if (lane < 16) {
    probs_out[(size_t)tok * NEXP + e] = p;
    atomicAdd(&sp[e], p);
  }

  // bf16 copy of this token's x row (coalesced)
  {
    float4 xc = *(const float4*)(x + (size_t)tok * DIM + lane * 4);
    ushort4 o;
    o.x = f2b(xc.x); o.y = f2b(xc.y); o.z = f2b(xc.z); o.w = f2b(xc.w);
    *(ushort4*)(xb + (size_t)tok * DIM + lane * 4) = o;
  }

  // top-2 argmax (strict >, low index wins)
  float p1 = p; int i1 = e;
  #pragma unroll
  for (int o = 1; o < 16; o <<= 1) {
    float po = __shfl_xor(p1, o, 64); int io = __shfl_xor(i1, o, 64);
    if (po > p1 || (po == p1 && io < i1)) { p1 = po; i1 = io; }
  }
  float pm = (e == i1) ? -1.f : p;
  float p2 = pm; int i2 = e;
  #pragma unroll
  for (int o = 1; o < 16; o <<= 1) {
    float po = __shfl_xor(p2, o, 64); int io = __shfl_xor(i2, o, 64);
    if (po > p2 || (po == p2 && io < i2)) { p2 = po; i2 = io; }
  }
  if (lane == 0) {
    float rs = 1.0f / (p1 + p2 + 1e-9f);
    int s0 = tok * 2;
    topw[s0] = p1 * rs;  topw[s0 + 1] = p2 * rs;
    sel[s0] = i1;        sel[s0 + 1] = i2;
    topi_out[s0] = (float)i1;  topi_out[s0 + 1] = (float)i2;
  }
  __syncthreads();
  if (tid < 16) g_partial[(size_t)tid * 4096 + blockIdx.x] = sp[tid];
}

// ---------- scatter: bucket fill + zbuf zero + last-block stats ----------
__global__ __launch_bounds__(256) void scatter_kernel(
    const int* __restrict__ sel, const float* __restrict__ topw,
    const float* __restrict__ g_partial,
    int* __restrict__ cursors, int* __restrict__ gdone,
    int* __restrict__ tok_of_pos, float* __restrict__ w_of_pos,
    float* __restrict__ zbuf, int* __restrict__ perm, float* __restrict__ lb_out)
{
  __shared__ int bcnt[16];
  __shared__ int bbase[16];
  int tid = threadIdx.x;
  if (tid < 16) bcnt[tid] = 0;
  __syncthreads();
  int s = blockIdx.x * 256 + tid;      // NSLOT = 128*256 exact
  int e = sel[s];
  int my = atomicAdd(&bcnt[e], 1);
  __syncthreads();
  if (tid < 16) bbase[tid] = atomicAdd(&cursors[tid], bcnt[tid]);
  __syncthreads();
  int idx = e * NSLOT + bbase[e] + my;
  tok_of_pos[idx] = s >> 1;
  w_of_pos[idx]   = topw[s];

  // zero this block's zbuf slice (replaces 16 MB memset launch)
  {
    float4 zz = {0.f, 0.f, 0.f, 0.f};
    float4* zp = (float4*)zbuf + (size_t)blockIdx.x * 8192 + tid;
    #pragma unroll
    for (int i = 0; i < 32; ++i) zp[i * 256] = zz;
  }

  // last block: stats (lb_loss + XCD-grouped tile table)
  __threadfence();
  __shared__ int lastS;
  if (tid == 0) lastS = (atomicAdd(gdone, 1) == 127) ? 1 : 0;
  __syncthreads();
  if (!lastS) return;

  __shared__ float sp[16];
  __shared__ int nt[16];
  __shared__ int P[9];
  __shared__ int ccnt[16];
  int wv = tid >> 6, lane = tid & 63;
  if (tid < 16) ccnt[tid] = atomicAdd(&cursors[tid], 0);   // coherent read
  #pragma unroll
  for (int ee = 0; ee < 4; ++ee) {
    int ex = wv * 4 + ee;
    float sacc = 0.f;
    #pragma unroll
    for (int j = 0; j < 64; ++j) sacc += g_partial[(size_t)ex * 4096 + j * 64 + lane];
    #pragma unroll
    for (int o = 32; o; o >>= 1) sacc += __shfl_xor(sacc, o, 64);
    if (lane == 0) sp[ex] = sacc;
  }
  __syncthreads();
  if (tid < 16) nt[tid] = (ccnt[tid] + RT - 1) / RT;
  __syncthreads();
  if (tid == 0) {
    float acc = 0.f;
    for (int e2 = 0; e2 < NEXP; ++e2)
      acc += ((float)ccnt[e2] / (32768.0f + 1e-9f)) * (sp[e2] * (1.0f / 16384.0f));
    lb_out[0] = 0.01f * 16.0f * acc;
    int pp = 0;
    for (int g = 0; g < 8; ++g) { P[g] = pp; pp += nt[g] + nt[g + 8]; }
    P[8] = pp;
  }
  __syncthreads();
  for (int t = tid; t < MAXT; t += 256) {
    int g = 0;
    #pragma unroll
    for (int gg = 1; gg < 8; ++gg) if (t >= P[gg]) g = gg;
    int v = -1;
    if (t < P[8]) {
      int r = t - P[g];
      int e2 = (r < nt[g]) ? g : g + 8;
      int mt = (r < nt[g]) ? r : r - nt[g];
      v = (e2 << 16) | mt;
    }
    perm[t] = v;
  }
}

// ---------- fused FFN: RT=64, 8 waves, swizzled LDS, af[4] intensity ----------
__global__ __launch_bounds__(512, 1) void ffn_kernel(
    const unsigned short* __restrict__ xb,
    const unsigned short* __restrict__ W1f, const unsigned short* __restrict__ W2f,
    const int* __restrict__ cursors, const int* __restrict__ perm,
    const int* __restrict__ tok_of_pos, const float* __restrict__ w_of_pos,
    float* __restrict__ zbuf)
{
  __shared__ __align__(16) unsigned short As[8 * 64 * 32];    // 32 KB
  __shared__ __align__(16) unsigned short Hs[16 * 64 * 32];   // 64 KB
  __shared__ float rwS[RT];
  __shared__ int   tokS[RT];

  int b = blockIdx.x;
  int rr = (b & 7) * XCDC + (b >> 3);       // XCD-pinned tile pick
  int pv = perm[rr];
  if (pv < 0) return;
  int e = pv >> 16, mtile = pv & 0xFFFF;
  int cnt = cursors[e];
  int base = e * NSLOT;
  int m0 = mtile * RT;

  int tid = threadIdx.x;
  if (tid < RT) {
    int rl = m0 + tid;
    tokS[tid] = (rl < cnt) ? tok_of_pos[base + rl] : -1;
    rwS[tid]  = (rl < cnt) ? w_of_pos[base + rl] : 0.f;
  }
  __syncthreads();

  // gather 64 X rows into As (swizzled fragment layout)
  #pragma unroll
  for (int q = 0; q < 4; ++q) {
    int idx = q * 512 + tid;
    int row = idx >> 5, cb = idx & 31;
    int tk = tokS[row];
    bf16x8 v = {0, 0, 0, 0, 0, 0, 0, 0};
    if (tk >= 0) v = *(const bf16x8*)(xb + (size_t)tk * DIM + cb * 8);
    int si = ((cb >> 2) * 2048 + row * 32 + (cb & 3) * 8) ^ ((row & 7) << 3);
    *(bf16x8*)&As[si] = v;
  }
  __syncthreads();

  int lane = tid & 63;
  int w = tid >> 6;              // wave 0..7
  int l15 = lane & 15, g = lane >> 4;

  // A-frags for all 4 row-blocks (128 VGPR, dead after GEMM1)
  bf16x8 af[4][8];
  #pragma unroll
  for (int mf = 0; mf < 4; ++mf) {
    int row = mf * 16 + l15;
    #pragma unroll
    for (int kb = 0; kb < 8; ++kb)
      af[mf][kb] = *(const bf16x8*)&As[(kb * 2048 + row * 32 + g * 8) ^ ((row & 7) << 3)];
  }

  // ---- GEMM1: H = gelu(A @ W1e); wave w owns h cols [w*64, +64) ----
  const unsigned short* W1e = W1f + (size_t)e * (8 * 512 * 32);
  #pragma unroll
  for (int cf = 0; cf < 4; ++cf) {
    int col0 = w * 64 + cf * 16;
    f32x4 ac[4];
    #pragma unroll
    for (int mf = 0; mf < 4; ++mf) ac[mf] = (f32x4){0.f, 0.f, 0.f, 0.f};
    #pragma unroll
    for (int kb = 0; kb < 8; ++kb) {
      bf16x8 bfr = *(const bf16x8*)(W1e + (size_t)(kb * 512 + col0 + l15) * 32 + g * 8);
      #pragma unroll
      for (int mf = 0; mf < 4; ++mf) ac[mf] = MFMA(af[mf][kb], bfr, ac[mf]);
    }
    int col = col0 + l15;
    #pragma unroll
    for (int mf = 0; mf < 4; ++mf) {
      #pragma unroll
      for (int reg = 0; reg < 4; ++reg) {
        int row = mf * 16 + g * 4 + reg;
        int si = ((col >> 5) * 2048 + row * 32 + (col & 31)) ^ ((row & 7) << 3);
        Hs[si] = f2b(gelu_f(ac[mf][reg]));
      }
    }
  }
  __syncthreads();

  // ---- GEMM2: y = (H @ W2e) * w; wave w owns y cols [w*32, +32) ----
  const unsigned short* W2e = W2f + (size_t)e * (16 * 256 * 32);
  bf16x8 b2[2][16];
  #pragma unroll
  for (int cf = 0; cf < 2; ++cf)
    #pragma unroll
    for (int kb = 0; kb < 16; ++kb)
      b2[cf][kb] = *(const bf16x8*)(W2e + (size_t)(kb * 256 + w * 32 + cf * 16 + l15) * 32 + g * 8);

  #pragma unroll
  for (int mf = 0; mf < 4; ++mf) {
    f32x4 ac0 = {0.f, 0.f, 0.f, 0.f}, ac1 = {0.f, 0.f, 0.f, 0.f};
    int rowa = mf * 16 + l15;
    #pragma unroll
    for (int kb = 0; kb < 16; ++kb) {
      bf16x8 hfr = *(const bf16x8*)&Hs[(kb * 2048 + rowa * 32 + g * 8) ^ ((rowa & 7) << 3)];
      ac0 = MFMA(hfr, b2[0][kb], ac0);
      ac1 = MFMA(hfr, b2[1][kb], ac1);
    }
    #pragma unroll
    for (int reg = 0; reg < 4; ++reg) {
      int row = mf * 16 + g * 4 + reg;
      int t = tokS[row];
      if (t >= 0) {
        float rw = rwS[row];
        atomicAdd(zbuf + (size_t)t * DIM + w * 32 + l15,      ac0[reg] * rw);
        atomicAdd(zbuf + (size_t)t * DIM + w * 32 + 16 + l15, ac1[reg] * rw);
      }
    }
  }
}

// ---------- combine + residual + LayerNorm ----------
__global__ __launch_bounds__(256) void combine_ln_kernel(
    const float* __restrict__ x, const float* __restrict__ zbuf,
    const float* __restrict__ gamma, const float* __restrict__ beta,
    float* __restrict__ outp)
{
  int wv = threadIdx.x >> 6, lane = threadIdx.x & 63;
  int tok = blockIdx.x * 4 + wv;
  int d0 = lane << 2;
  float4 xv = *(const float4*)(x + (size_t)tok * DIM + d0);
  float4 mv = *(const float4*)(zbuf + (size_t)tok * DIM + d0);
  float z0 = xv.x + mv.x, z1 = xv.y + mv.y, z2 = xv.z + mv.z, z3 = xv.w + mv.w;
  float s = z0 + z1 + z2 + z3;
  float q = z0 * z0 + z1 * z1 + z2 * z2 + z3 * z3;
  #pragma unroll
  for (int off = 32; off > 0; off >>= 1) {
    s += __shfl_xor(s, off, 64);
    q += __shfl_xor(q, off, 64);
  }
  float mu  = s * (1.0f / 256.0f);
  float var = q * (1.0f / 256.0f) - mu * mu;
  float inv = rsqrtf(var + 1e-5f);
  float4 gv = *(const float4*)(gamma + d0);
  float4 bv = *(const float4*)(beta + d0);
  float4 ov;
  ov.x = (z0 - mu) * inv * gv.x + bv.x;
  ov.y = (z1 - mu) * inv * gv.y + bv.y;
  ov.z = (z2 - mu) * inv * gv.z + bv.z;
  ov.w = (z3 - mu) * inv * gv.w + bv.w;
  *(float4*)(outp + (size_t)tok * DIM + d0) = ov;
}

extern "C" void kernel_launch(void* const* d_in, const int* in_sizes, int n_in,
                              void* d_out, int out_size, void* d_ws, size_t ws_size,
                              hipStream_t stream)
{
  const float* x     = (const float*)d_in[0];
  const float* Wr    = (const float*)d_in[1];
  const float* W1    = (const float*)d_in[2];
  const float* W2    = (const float*)d_in[3];
  const float* gamma = (const float*)d_in[4];
  const float* beta  = (const float*)d_in[5];

  float* ob = (float*)d_out;
  float* out_main  = ob;
  float* lb_out    = ob + (size_t)N_TOK * DIM;
  float* probs_out = ob + (size_t)N_TOK * DIM + 1;
  float* topi_out  = ob + (size_t)N_TOK * DIM + 1 + (size_t)N_TOK * NEXP;

  char* ws = (char*)d_ws;
  int*   cursors    = (int*)(ws + 0);                    // 64 B [zeroed]
  int*   gdone      = (int*)(ws + 64);                   // 4 B  [zeroed]
  int*   perm       = (int*)(ws + 1024);                 // 528 ints
  float* g_partial  = (float*)(ws + 65536);              // 256 KB
  float* topw       = (float*)(ws + 327680);             // 128 KB
  int*   sel        = (int*)(ws + 458752);               // 128 KB
  int*   tok_of_pos = (int*)(ws + 589824);               // 2 MB (16 arenas x 32768)
  float* w_of_pos   = (float*)(ws + 2686976);            // 2 MB
  unsigned short* xb  = (unsigned short*)(ws + 4980736);    // 8 MB
  unsigned short* W1f = (unsigned short*)(ws + 13369344);   // 4 MB
  unsigned short* W2f = (unsigned short*)(ws + 17563648);   // 4 MB
  float* zbuf       = (float*)(ws + 21757952);              // 16 MB; total ~36.7 MB

  hipMemsetAsync(cursors, 0, 128, stream);
  prep_kernel<<<4096, 256, 0, stream>>>(W1, W2, W1f, W2f);
  router_kernel<<<N_TOK / 4, 256, 0, stream>>>(x, Wr, probs_out, topi_out, topw, sel, g_partial, xb);
  scatter_kernel<<<NSLOT / 256, 256, 0, stream>>>(sel, topw, g_partial, cursors, gdone,
                                                  tok_of_pos, w_of_pos, zbuf, perm, lb_out);
  ffn_kernel<<<MAXT, 512, 0, stream>>>(xb, W1f, W2f, cursors, perm, tok_of_pos, w_of_pos, zbuf);
  combine_ln_kernel<<<N_TOK / 4, 256, 0, stream>>>(x, zbuf, gamma, beta, out_main);
}